// Round 3
// baseline (340.156 us; speedup 1.0000x reference)
//
#include <hip/hip_runtime.h>
#include <hip/hip_cooperative_groups.h>
#include <stdint.h>

namespace cg = cooperative_groups;

#define NSK 1000
#define TT  200
#define BB  64
#define NROW (BB * TT)      // 12800
#define CH  20              // scan chunk (steps); red = CH*1024 floats = 80 KB

__device__ __forceinline__ unsigned ulane_bcast(unsigned v, int l) {
  return __builtin_amdgcn_readlane(v, l);
}
__device__ __forceinline__ float frcp(float x) { return __builtin_amdgcn_rcpf(x); }
__device__ __forceinline__ float sigm(float x) { return frcp(1.f + __expf(-x)); }
__device__ __forceinline__ float tanh_fast(float x) {
  return fmaf(-2.f, frcp(1.f + __expf(2.f * x)), 1.f);   // 1 - 2/(1+e^2x)
}

typedef _Float16 half2v __attribute__((ext_vector_type(2)));
union H2U { unsigned u; half2v h; };
__device__ __forceinline__ unsigned pack2h(float a, float b) {
  H2U x; x.h = (half2v){(_Float16)a, (_Float16)b}; return x.u;
}
__device__ __forceinline__ unsigned short f16bits(float x) {
  H2U u; u.h = (half2v){(_Float16)x, (_Float16)0.f}; return (unsigned short)(u.u & 0xffffu);
}
__device__ __forceinline__ float f16lo(unsigned bits) {
  H2U u; u.u = bits; return (float)u.h.x;
}
__device__ __forceinline__ float f16hi(unsigned bits) {
  H2U u; u.u = bits; return (float)u.h.y;
}
__device__ __forceinline__ float dot2h(unsigned sp, unsigned wp, float acc) {
#if __has_builtin(__builtin_amdgcn_fdot2)
  H2U s, w; s.u = sp; w.u = wp;
  return __builtin_amdgcn_fdot2(s.h, w.h, acc, false);
#else
  H2U s, w; s.u = sp; w.u = wp;
  return fmaf((float)s.h.y, (float)w.h.y, fmaf((float)s.h.x, (float)w.h.x, acc));
#endif
}
__device__ __forceinline__ unsigned pack_pairs(float v) {
  const int lane = threadIdx.x & 63;
  float a = __shfl(v, 2 * lane);       // lanes 0..31 cover all 32 pairs
  float b = __shfl(v, 2 * lane + 1);
  return pack2h(a, b);
}

// ============ One cooperative kernel: 256 blocks (4/batch) x 1024 thr ============
// Phase A: w/e/a, 50 rows/block -> ws.   grid.sync
// Phase B: scan, 16 m-rows/block (RW=1/wave) -> f16 partials p0..p3.  grid.sync
// Phase C: f/p, ~50 outputs/block -> out.
// LDS overlay (80 KB, 1 block/CU): sw(30.7K) in A | red(80K) in B | sf(18.4K) in C.
__global__ __launch_bounds__(1024) void dkvmn_coop(
    const int* __restrict__ skills, const int* __restrict__ responses,
    const float* __restrict__ k_emb, const float* __restrict__ v_emb,
    const float* __restrict__ Mk, const float* __restrict__ Mv0,
    const float* __restrict__ fW, const float* __restrict__ fb,
    const float* __restrict__ eW, const float* __restrict__ eb,
    const float* __restrict__ aW, const float* __restrict__ ab,
    const float* __restrict__ pW, const float* __restrict__ pb,
    unsigned* __restrict__ ea_ws, unsigned short* __restrict__ w16_ws,
    unsigned short* __restrict__ p0, unsigned short* __restrict__ p1,
    unsigned short* __restrict__ p2, unsigned short* __restrict__ p3,
    float* __restrict__ out)
{
  __shared__ __align__(16) unsigned char smraw[CH * 1024 * 4];  // 81920 B
  unsigned* sw = (unsigned*)smraw;     // phase A weights (Mk|eW|aW f16, stride 40)
  unsigned* sf = (unsigned*)smraw;     // phase C weights (fW f16, stride 72)
  float*   red = (float*)smraw;        // phase B partial-read buffer [CH][1024]

  const int tid  = threadIdx.x;
  const int wave = tid >> 6, lane = tid & 63;
  const int g = blockIdx.x, b = g >> 2, s = g & 3;

  // ---- stage Mk/eW/aW (f16-pack, swizzled stride 40) ----
  for (int ch = tid; ch < 1536; ch += 1024) {
    const int mat = ch >> 9, rem = ch & 511;
    const int j = rem >> 3, cc = rem & 7;
    const float4* src = (mat == 0) ? (const float4*)Mk
                      : (mat == 1) ? (const float4*)eW : (const float4*)aW;
    const float4 f0 = src[j * 16 + cc * 2];
    const float4 f1 = src[j * 16 + cc * 2 + 1];
    uint4 pk;
    pk.x = pack2h(f0.x, f0.y); pk.y = pack2h(f0.z, f0.w);
    pk.z = pack2h(f1.x, f1.y); pk.w = pack2h(f1.z, f1.w);
    *(uint4*)&sw[mat * 2560 + j * 40 + ((cc + j) & 7) * 4] = pk;
  }
  __syncthreads();

  // ================= Phase A: rows b*200 + s*50 + [0,50) =================
  {
    const float ebl = eb[lane], abl = ab[lane];
    #pragma unroll 1
    for (int it = 0; it < 2; ++it) {
      const int rl = it * 32 + wave * 2;             // 0..48 even
      if (rl < 50) {
        float kv[2], vv[2];
        #pragma unroll
        for (int i = 0; i < 2; ++i) {
          const int row = b * TT + s * 50 + rl + i;
          const int sk = skills[row];
          int rr = responses[row]; rr = (rr > -1) ? rr : 0;   // masked_r
          kv[i] = k_emb[(size_t)sk * 64 + lane];
          vv[i] = v_emb[(size_t)(sk + NSK * rr) * 64 + lane];
        }
        unsigned kp[2], vp[2];
        #pragma unroll
        for (int i = 0; i < 2; ++i) { kp[i] = pack_pairs(kv[i]); vp[i] = pack_pairs(vv[i]); }

        float accK[2] = {0.f, 0.f}, accE[2] = {0.f, 0.f}, accA[2] = {0.f, 0.f};
        #pragma unroll 1
        for (int h = 0; h < 2; ++h) {
          uint4 qm[4], qe[4], qa[4];
          #pragma unroll
          for (int c = 0; c < 4; ++c) {
            const int off = lane * 40 + (((h * 4 + c) + lane) & 7) * 4;
            qm[c] = *(const uint4*)&sw[off];
            qe[c] = *(const uint4*)&sw[2560 + off];
            qa[c] = *(const uint4*)&sw[5120 + off];
          }
          #pragma unroll
          for (int i = 0; i < 2; ++i) {
            #pragma unroll
            for (int c = 0; c < 4; ++c) {
              const unsigned um[4] = {qm[c].x, qm[c].y, qm[c].z, qm[c].w};
              const unsigned ue[4] = {qe[c].x, qe[c].y, qe[c].z, qe[c].w};
              const unsigned ua[4] = {qa[c].x, qa[c].y, qa[c].z, qa[c].w};
              #pragma unroll
              for (int m = 0; m < 4; ++m) {
                const int idx = (h * 4 + c) * 4 + m;   // pair index 0..31
                const unsigned spk = ulane_bcast(kp[i], idx);
                const unsigned spv = ulane_bcast(vp[i], idx);
                accK[i] = dot2h(spk, um[m], accK[i]);
                accE[i] = dot2h(spv, ue[m], accE[i]);
                accA[i] = dot2h(spv, ua[m], accA[i]);
              }
            }
          }
        }
        #pragma unroll
        for (int i = 0; i < 2; ++i) {
          const int row = b * TT + s * 50 + rl + i;
          float mx = accK[i];
          #pragma unroll
          for (int off = 32; off; off >>= 1) mx = fmaxf(mx, __shfl_xor(mx, off));
          float ex = __expf(accK[i] - mx);
          float sm = ex;
          #pragma unroll
          for (int off = 32; off; off >>= 1) sm += __shfl_xor(sm, off);
          const float wv  = ex * frcp(sm);
          const float evv = sigm(accE[i] + ebl);
          const float avv = tanh_fast(accA[i] + abl);
          ea_ws[(size_t)row * 64 + lane]  = pack2h(evv, avv);
          w16_ws[(size_t)row * 64 + lane] = f16bits(wv);
        }
      }
    }
  }
  __threadfence();
  cg::this_grid().sync();

  // ================= Phase B: scan, m-row m0 = s*16 + wave (RW=1) =================
  {
    const int m0 = s * 16 + wave;
    unsigned short* ps = (s == 0) ? p0 : (s == 1) ? p1 : (s == 2) ? p2 : p3;
    const size_t base = (size_t)b * TT;
    float Mv = Mv0[(size_t)m0 * 64 + lane];

    #pragma unroll 1
    for (int t0 = 0; t0 < TT; t0 += CH) {            // 10 chunks
      unsigned eab[CH], wvb[CH];
      #pragma unroll
      for (int k = 0; k < CH; ++k) {
        eab[k] = ea_ws[(base + t0 + k) * 64 + lane];
        wvb[k] = (unsigned)w16_ws[(base + t0 + k) * 64 + m0];  // uniform per wave
      }
      #pragma unroll
      for (int k = 0; k < CH; ++k) {
        const float ev = f16lo(eab[k]), av = f16hi(eab[k]);
        const float wm = f16lo(wvb[k]);              // no readlane needed (RW=1)
        red[k * 1024 + wave * 64 + lane] = wm * Mv;  // read uses PRE-update Mv
        const float tp = fmaf(-ev, Mv, av);          // a - e*Mv
        Mv = fmaf(wm, tp, Mv);                       // Mv += w*(a - e*Mv)
      }
      __syncthreads();
      for (int k = wave; k < CH; k += 16) {          // waves 0..15 reduce 16 partials
        const float* rr = red + k * 1024;
        float v = ((rr[lane]        + rr[64 + lane])  + (rr[128 + lane] + rr[192 + lane]))
                + ((rr[256 + lane]  + rr[320 + lane]) + (rr[384 + lane] + rr[448 + lane]));
        v +=     ((rr[512 + lane]  + rr[576 + lane]) + (rr[640 + lane] + rr[704 + lane]))
                + ((rr[768 + lane]  + rr[832 + lane]) + (rr[896 + lane] + rr[960 + lane]));
        ps[(base + t0 + k) * 64 + lane] = f16bits(v);
      }
      __syncthreads();
    }
  }
  __threadfence();
  cg::this_grid().sync();

  // ---- stage fW (f16-pack, swizzled stride 72) — overlays red ----
  for (int ch = tid; ch < 1024; ch += 1024) {
    const int j = ch >> 4, cc = ch & 15;
    const float4 f0 = ((const float4*)fW)[j * 32 + cc * 2];
    const float4 f1 = ((const float4*)fW)[j * 32 + cc * 2 + 1];
    uint4 pk;
    pk.x = pack2h(f0.x, f0.y); pk.y = pack2h(f0.z, f0.w);
    pk.z = pack2h(f1.x, f1.y); pk.w = pack2h(f1.z, f1.w);
    *(uint4*)&sf[j * 72 + ((cc + j) & 15) * 4] = pk;
  }
  __syncthreads();

  // ================= Phase C: outputs t = s*50 + [0,50) (s=3: 49) =================
  {
    const float fbl = fb[lane], pwl = pW[lane], pb0 = pb[0];
    const int cnt = (s == 3) ? 49 : 50;
    #pragma unroll 1
    for (int it = 0; it < 2; ++it) {
      const int ol = it * 32 + wave * 2;
      if (ol >= cnt) continue;
      const int o0 = s * 50 + ol;
      const bool two = (ol + 1 < cnt);
      const int oo[2] = {o0, two ? o0 + 1 : o0};

      float rv[2], kc[2];
      #pragma unroll
      for (int i = 0; i < 2; ++i) {
        const size_t row = (size_t)b * TT + oo[i] + 1;   // out t uses read at step t+1
        rv[i] = (f16lo((unsigned)p0[row * 64 + lane])
               + f16lo((unsigned)p1[row * 64 + lane]))
              + (f16lo((unsigned)p2[row * 64 + lane])
               + f16lo((unsigned)p3[row * 64 + lane]));
        kc[i] = k_emb[(size_t)skills[row] * 64 + lane];
      }
      unsigned rvp[2], kvp[2];
      #pragma unroll
      for (int i = 0; i < 2; ++i) {
        rvp[i] = pack_pairs(rv[i]);
        kvp[i] = pack_pairs(kc[i]);
      }

      float acc[2] = {fbl, fbl};
      #pragma unroll 1
      for (int h = 0; h < 4; ++h) {
        uint4 qf[4];
        #pragma unroll
        for (int c = 0; c < 4; ++c)
          qf[c] = *(const uint4*)&sf[lane * 72 + (((h * 4 + c) + lane) & 15) * 4];
        #pragma unroll
        for (int i = 0; i < 2; ++i) {
          #pragma unroll
          for (int c = 0; c < 4; ++c) {
            const unsigned uu[4] = {qf[c].x, qf[c].y, qf[c].z, qf[c].w};
            #pragma unroll
            for (int m = 0; m < 4; ++m) {
              const int idx = (h * 4 + c) * 4 + m;     // pair index 0..63
              const unsigned sp = (idx < 32) ? ulane_bcast(rvp[i], idx)
                                             : ulane_bcast(kvp[i], idx - 32);
              acc[i] = dot2h(sp, uu[m], acc[i]);
            }
          }
        }
      }

      float f0 = tanh_fast(acc[0]) * pwl;
      float f1 = tanh_fast(acc[1]) * pwl;
      #pragma unroll
      for (int off = 32; off; off >>= 1) {
        f0 += __shfl_xor(f0, off);
        f1 += __shfl_xor(f1, off);
      }
      if (lane == 0) {
        out[(size_t)b * (TT - 1) + oo[0]] = sigm(f0 + pb0);
        if (two) out[(size_t)b * (TT - 1) + oo[1]] = sigm(f1 + pb0);
      }
    }
  }
}

extern "C" void kernel_launch(void* const* d_in, const int* in_sizes, int n_in,
                              void* d_out, int out_size, void* d_ws, size_t ws_size,
                              hipStream_t stream) {
  const int* skills    = (const int*)d_in[0];
  const int* responses = (const int*)d_in[1];
  const float* k_emb   = (const float*)d_in[2];
  const float* v_emb   = (const float*)d_in[3];
  const float* Mk      = (const float*)d_in[4];
  const float* Mv0     = (const float*)d_in[5];
  const float* fW      = (const float*)d_in[6];
  const float* fb      = (const float*)d_in[7];
  const float* eW      = (const float*)d_in[8];
  const float* eb      = (const float*)d_in[9];
  const float* aW      = (const float*)d_in[10];
  const float* ab      = (const float*)d_in[11];
  const float* pW      = (const float*)d_in[12];
  const float* pb      = (const float*)d_in[13];
  (void)in_sizes; (void)n_in; (void)out_size; (void)ws_size;

  // f16-packed scratch: ea (3.3MB) | w16 (1.6MB) | p0..p3 (1.6MB each)
  unsigned* ea_ws        = (unsigned*)d_ws;
  unsigned short* w16_ws = (unsigned short*)(ea_ws + (size_t)NROW * 64);
  unsigned short* p0     = w16_ws + (size_t)NROW * 64;
  unsigned short* p1     = p0 + (size_t)NROW * 64;
  unsigned short* p2     = p1 + (size_t)NROW * 64;
  unsigned short* p3     = p2 + (size_t)NROW * 64;
  float* out             = (float*)d_out;

  void* args[] = {
    (void*)&skills, (void*)&responses, (void*)&k_emb, (void*)&v_emb,
    (void*)&Mk, (void*)&Mv0, (void*)&fW, (void*)&fb, (void*)&eW, (void*)&eb,
    (void*)&aW, (void*)&ab, (void*)&pW, (void*)&pb,
    (void*)&ea_ws, (void*)&w16_ws, (void*)&p0, (void*)&p1, (void*)&p2, (void*)&p3,
    (void*)&out
  };
  hipLaunchCooperativeKernel((const void*)dkvmn_coop, dim3(BB * 4), dim3(1024),
                             args, 0, stream);
}

// Round 4
// 121.949 us; speedup vs baseline: 2.7893x; 2.7893x over previous
//
#include <hip/hip_runtime.h>
#include <stdint.h>

#define NSK 1000
#define TT  200
#define BB  64
#define NROW (BB * TT)      // 12800
#define NOUT (BB * (TT-1))  // 12736
#define CH  20              // scan pipeline depth (steps); TT/CH = 10 chunks (even)
#define RW  4               // scan Mv rows per wave (4-way M split: 4 blocks/batch)

__device__ __forceinline__ unsigned ulane_bcast(unsigned v, int l) {
  return __builtin_amdgcn_readlane(v, l);
}
__device__ __forceinline__ float frcp(float x) { return __builtin_amdgcn_rcpf(x); }
__device__ __forceinline__ float sigm(float x) { return frcp(1.f + __expf(-x)); }
__device__ __forceinline__ float tanh_fast(float x) {
  return fmaf(-2.f, frcp(1.f + __expf(2.f * x)), 1.f);   // 1 - 2/(1+e^2x)
}

typedef _Float16 half2v __attribute__((ext_vector_type(2)));
typedef _Float16 v8h __attribute__((ext_vector_type(8)));   // MFMA A/B frag (4 VGPR)
typedef float    v4f __attribute__((ext_vector_type(4)));   // MFMA C/D frag
union H2U { unsigned u; half2v h; };
__device__ __forceinline__ unsigned pack2h(float a, float b) {
  H2U x; x.h = (half2v){(_Float16)a, (_Float16)b}; return x.u;
}
__device__ __forceinline__ unsigned short f16bits(float x) {
  H2U u; u.h = (half2v){(_Float16)x, (_Float16)0.f}; return (unsigned short)(u.u & 0xffffu);
}
__device__ __forceinline__ float f16lo(unsigned bits) {
  H2U u; u.u = bits; return (float)u.h.x;
}
__device__ __forceinline__ float f16hi(unsigned bits) {
  H2U u; u.u = bits; return (float)u.h.y;
}
__device__ __forceinline__ float dot2h(unsigned sp, unsigned wp, float acc) {
#if __has_builtin(__builtin_amdgcn_fdot2)
  H2U s, w; s.u = sp; w.u = wp;
  return __builtin_amdgcn_fdot2(s.h, w.h, acc, false);
#else
  H2U s, w; s.u = sp; w.u = wp;
  return fmaf((float)s.h.y, (float)w.h.y, fmaf((float)s.h.x, (float)w.h.x, acc));
#endif
}
__device__ __forceinline__ unsigned pack_pairs(float v) {
  const int lane = threadIdx.x & 63;
  float a = __shfl(v, 2 * lane);       // lanes 0..31 cover all 32 pairs
  float b = __shfl(v, 2 * lane + 1);
  return pack2h(a, b);
}
__device__ __forceinline__ v8h pk8(float4 x0, float4 x1) {
  return (v8h){(_Float16)x0.x, (_Float16)x0.y, (_Float16)x0.z, (_Float16)x0.w,
               (_Float16)x1.x, (_Float16)x1.y, (_Float16)x1.z, (_Float16)x1.w};
}

// ============ Pass A (MFMA): 400 blocks x 128 thr, 16 rows/wave ============
// out[r][m] = K(r)·Mk(m); e/a likewise from V.  3 GEMMs [16x64]x[64x64] per wave
// via v_mfma_f32_16x16x32_f16 (24 MFMAs).  A: row=lane&15, k=(lane>>4)*8+e.
// B: col=lane&15, k=(lane>>4)*8+e.  D: col=lane&15, row=(lane>>4)*4+reg.
__global__ __launch_bounds__(128) void wea_mfma(
    const int* __restrict__ skills, const int* __restrict__ responses,
    const float* __restrict__ k_emb, const float* __restrict__ v_emb,
    const float* __restrict__ Mk, const float* __restrict__ eW,
    const float* __restrict__ eb, const float* __restrict__ aW,
    const float* __restrict__ ab,
    unsigned* __restrict__ ea_ws, unsigned short* __restrict__ w16_ws)
{
  const int tid  = threadIdx.x;
  const int wv   = tid >> 6, lane = tid & 63;
  const int tile = blockIdx.x * 2 + wv;              // 400*2 = 800 tiles
  const int r0   = tile * 16;
  const int lr   = lane & 15;                        // A-row / B-col / D-col
  const int lg   = lane >> 4;                        // k-group (8 f16 each)

  // gather per-row skill / value-row index (row = r0 + lr)
  const int sk = skills[r0 + lr];
  int rr = responses[r0 + lr]; rr = (rr > -1) ? rr : 0;   // masked_r
  const int vrow = sk + NSK * rr;

  // A-fragments: k and v rows, 2 K-tiles (K=64)
  const float4* kq = (const float4*)(k_emb + (size_t)sk * 64);
  const float4* vq = (const float4*)(v_emb + (size_t)vrow * 64);
  v8h ak[2], av[2];
  #pragma unroll
  for (int t = 0; t < 2; ++t) {
    const int o = t * 8 + lg * 2;                    // float4 index within row
    ak[t] = pk8(kq[o], kq[o + 1]);
    av[t] = pk8(vq[o], vq[o + 1]);
  }

  // per-c bias values (j = 16c + lr)
  float ebv[4], abv[4];
  #pragma unroll
  for (int c = 0; c < 4; ++c) { ebv[c] = eb[16 * c + lr]; abv[c] = ab[16 * c + lr]; }

  v4f acK[4], acE[4], acA[4];
  #pragma unroll
  for (int c = 0; c < 4; ++c) {
    acK[c] = (v4f){0.f, 0.f, 0.f, 0.f};
    acE[c] = (v4f){0.f, 0.f, 0.f, 0.f};
    acA[c] = (v4f){0.f, 0.f, 0.f, 0.f};
  }

  // B-fragments loaded per col-tile; 6 MFMAs per col-tile
  #pragma unroll
  for (int c = 0; c < 4; ++c) {
    const float4* mq = (const float4*)(Mk + (size_t)(16 * c + lr) * 64);
    const float4* eq = (const float4*)(eW + (size_t)(16 * c + lr) * 64);
    const float4* aq = (const float4*)(aW + (size_t)(16 * c + lr) * 64);
    #pragma unroll
    for (int t = 0; t < 2; ++t) {
      const int o = t * 8 + lg * 2;
      const v8h bm = pk8(mq[o], mq[o + 1]);
      const v8h be = pk8(eq[o], eq[o + 1]);
      const v8h ba = pk8(aq[o], aq[o + 1]);
      acK[c] = __builtin_amdgcn_mfma_f32_16x16x32_f16(ak[t], bm, acK[c], 0, 0, 0);
      acE[c] = __builtin_amdgcn_mfma_f32_16x16x32_f16(av[t], be, acE[c], 0, 0, 0);
      acA[c] = __builtin_amdgcn_mfma_f32_16x16x32_f16(av[t], ba, acA[c], 0, 0, 0);
    }
  }

  // softmax over m (64 cols) for each of the 4 rows this lane-group holds.
  // Row r = lg*4 + q lives in the 16 consecutive lanes lg*16..lg*16+15.
  float rs[4];
  #pragma unroll
  for (int q = 0; q < 4; ++q) {
    float m = fmaxf(fmaxf(acK[0][q], acK[1][q]), fmaxf(acK[2][q], acK[3][q]));
    #pragma unroll
    for (int off = 8; off; off >>= 1) m = fmaxf(m, __shfl_xor(m, off));
    float s = 0.f;
    #pragma unroll
    for (int c = 0; c < 4; ++c) {
      acK[c][q] = __expf(acK[c][q] - m);
      s += acK[c][q];
    }
    #pragma unroll
    for (int off = 8; off; off >>= 1) s += __shfl_xor(s, off);
    rs[q] = frcp(s);
  }

  // epilogue: w (softmax), e (sigmoid), a (tanh) -> f16 workspace
  #pragma unroll
  for (int c = 0; c < 4; ++c) {
    const int j = 16 * c + lr;
    #pragma unroll
    for (int q = 0; q < 4; ++q) {
      const int row = r0 + lg * 4 + q;
      w16_ws[(size_t)row * 64 + j] = f16bits(acK[c][q] * rs[q]);
      const float ev = sigm(acE[c][q] + ebv[c]);
      const float avv = tanh_fast(acA[c][q] + abv[c]);
      ea_ws[(size_t)row * 64 + j] = pack2h(ev, avv);
    }
  }
}

// ---- scan helpers (f16-packed inputs, CH=20) ----
__device__ __forceinline__ void load_chunk(
    const unsigned* __restrict__ eap, const unsigned short* __restrict__ wp,
    int t0, int wl, int lane, unsigned* eab, unsigned* wvb)
{
  #pragma unroll
  for (int k = 0; k < CH; ++k) {
    eab[k] = eap[(t0 + k) * 64 + lane];
    wvb[k] = (unsigned)wp[(t0 + k) * 64 + wl];
  }
}

__device__ __forceinline__ void compute_chunk(
    float* Mv, const unsigned* eab, const unsigned* wvb,
    float* __restrict__ red, int wave, int lane)
{
  #pragma unroll
  for (int k = 0; k < CH; ++k) {
    const float ev = f16lo(eab[k]), av = f16hi(eab[k]);
    float rp = 0.f;
    #pragma unroll
    for (int i = 0; i < RW; ++i) {
      const float wm = f16lo(ulane_bcast(wvb[k], i));  // w[m0+i] sits in lane i (0..3)
      rp = fmaf(wm, Mv[i], rp);            // read uses PRE-update Mv
      float tp = fmaf(-ev, Mv[i], av);     // a - e*Mv
      Mv[i] = fmaf(wm, tp, Mv[i]);         // Mv += w*(a - e*Mv)
    }
    red[k * 256 + wave * 64 + lane] = rp;  // per-wave partial -> LDS
  }
}

// in-block reduce: wave w sums steps w*5..w*5+4 of the chunk -> f16 partial
__device__ __forceinline__ void reduce_store(
    const float* __restrict__ red, int ch, int base, int wave, int lane,
    unsigned short* __restrict__ ps)
{
  #pragma unroll
  for (int u = 0; u < 5; ++u) {
    const int k = wave * 5 + u;
    const float* rr = red + k * 256;
    const float v = (rr[lane] + rr[64 + lane]) + (rr[128 + lane] + rr[192 + lane]);
    ps[(size_t)(base + ch * CH + k) * 64 + lane] = f16bits(v);
  }
}

// ============ Pass B: 256 blocks x 256 thr, 4 blocks/batch (16 M-rows each) ============
__global__ __launch_bounds__(256) void scan_kernel(
    const float* __restrict__ Mv0,
    const unsigned* __restrict__ ea_ws, const unsigned short* __restrict__ w16_ws,
    unsigned short* __restrict__ p0, unsigned short* __restrict__ p1,
    unsigned short* __restrict__ p2, unsigned short* __restrict__ p3)
{
  __shared__ float red[2][CH * 256];                 // 40 KB
  const int b    = blockIdx.x >> 2;
  const int s    = blockIdx.x & 3;
  const int wave = threadIdx.x >> 6;
  const int lane = threadIdx.x & 63;
  const int base = b * TT;
  const int m0   = s * 16 + wave * RW;
  const int wl   = m0 + (lane & (RW - 1));
  unsigned short* ps = (s == 0) ? p0 : (s == 1) ? p1 : (s == 2) ? p2 : p3;

  float Mv[RW];
  #pragma unroll
  for (int i = 0; i < RW; ++i) Mv[i] = Mv0[(size_t)(m0 + i) * 64 + lane];

  const unsigned* eap = ea_ws + (size_t)base * 64;
  const unsigned short* wp = w16_ws + (size_t)base * 64;

  unsigned ea0[CH], wv0[CH], ea1[CH], wv1[CH];
  load_chunk(eap, wp, 0, wl, lane, ea0, wv0);
  for (int ch = 0; ch < TT / CH; ch += 2) {          // 10 chunks
    if ((ch + 1) * CH < TT)
      load_chunk(eap, wp, (ch + 1) * CH, wl, lane, ea1, wv1);
    compute_chunk(Mv, ea0, wv0, red[0], wave, lane);
    __syncthreads();
    reduce_store(red[0], ch, base, wave, lane, ps);
    if ((ch + 2) * CH < TT)
      load_chunk(eap, wp, (ch + 2) * CH, wl, lane, ea0, wv0);
    if ((ch + 1) * CH < TT) {
      compute_chunk(Mv, ea1, wv1, red[1], wave, lane);
      __syncthreads();
      reduce_store(red[1], ch + 1, base, wave, lane, ps);
    }
  }
}

// ============ Pass C: 1592 blocks x 256 thr, 2 outputs/wave ============
__global__ __launch_bounds__(256) void fp_kernel(
    const int* __restrict__ skills, const float* __restrict__ k_emb,
    const float* __restrict__ fW, const float* __restrict__ fb,
    const float* __restrict__ pW, const float* __restrict__ pb,
    const unsigned short* __restrict__ p0, const unsigned short* __restrict__ p1,
    const unsigned short* __restrict__ p2, const unsigned short* __restrict__ p3,
    float* __restrict__ out)
{
  __shared__ unsigned sf[64 * 72];                   // 18432 B
  const int tid = threadIdx.x;
  for (int ch = tid; ch < 1024; ch += 256) {         // f16-pack fW, stride 72
    const int j = ch >> 4, cc = ch & 15;
    const float4 f0 = ((const float4*)fW)[j * 32 + cc * 2];
    const float4 f1 = ((const float4*)fW)[j * 32 + cc * 2 + 1];
    uint4 pk;
    pk.x = pack2h(f0.x, f0.y); pk.y = pack2h(f0.z, f0.w);
    pk.z = pack2h(f1.x, f1.y); pk.w = pack2h(f1.z, f1.w);
    *(uint4*)&sf[j * 72 + ((cc + j) & 15) * 4] = pk;
  }
  __syncthreads();

  const int wave = tid >> 6, lane = tid & 63;
  const float fbl = fb[lane], pwl = pW[lane], pb0 = pb[0];
  const int p = blockIdx.x * 4 + wave;               // pair id, 1592*4 = 6368 exact

  float rv[2], kc[2];
  int bsave[2], tsave[2];
  #pragma unroll
  for (int i = 0; i < 2; ++i) {
    const unsigned idx = 2u * p + i;
    const unsigned b = idx / 199u;
    const int row = (int)(idx + b + 1u);
    bsave[i] = (int)b; tsave[i] = (int)(idx - b * 199u);
    rv[i] = (f16lo((unsigned)p0[(size_t)row * 64 + lane])
           + f16lo((unsigned)p1[(size_t)row * 64 + lane]))
          + (f16lo((unsigned)p2[(size_t)row * 64 + lane])
           + f16lo((unsigned)p3[(size_t)row * 64 + lane]));
    kc[i] = k_emb[(size_t)skills[row] * 64 + lane];
  }
  unsigned rvp[2], kvp[2];
  #pragma unroll
  for (int i = 0; i < 2; ++i) {
    rvp[i] = pack_pairs(rv[i]);
    kvp[i] = pack_pairs(kc[i]);
  }

  float acc[2] = {fbl, fbl};
  #pragma unroll 1
  for (int h = 0; h < 4; ++h) {                      // quarters: 4 uint4 (32 inputs)
    uint4 qf[4];
    #pragma unroll
    for (int c = 0; c < 4; ++c)
      qf[c] = *(const uint4*)&sf[lane * 72 + (((h * 4 + c) + lane) & 15) * 4];
    #pragma unroll
    for (int i = 0; i < 2; ++i) {
      #pragma unroll
      for (int c = 0; c < 4; ++c) {
        const unsigned uu[4] = {qf[c].x, qf[c].y, qf[c].z, qf[c].w};
        #pragma unroll
        for (int m = 0; m < 4; ++m) {
          const int idx = (h * 4 + c) * 4 + m;       // pair index 0..63
          const unsigned sp = (idx < 32) ? ulane_bcast(rvp[i], idx)
                                         : ulane_bcast(kvp[i], idx - 32);
          acc[i] = dot2h(sp, uu[m], acc[i]);
        }
      }
    }
  }

  float f0 = tanh_fast(acc[0]) * pwl;
  float f1 = tanh_fast(acc[1]) * pwl;
  #pragma unroll
  for (int off = 32; off; off >>= 1) {
    f0 += __shfl_xor(f0, off);
    f1 += __shfl_xor(f1, off);
  }
  if (lane == 0) {
    out[(size_t)bsave[0] * (TT - 1) + tsave[0]] = sigm(f0 + pb0);
    out[(size_t)bsave[1] * (TT - 1) + tsave[1]] = sigm(f1 + pb0);
  }
}

extern "C" void kernel_launch(void* const* d_in, const int* in_sizes, int n_in,
                              void* d_out, int out_size, void* d_ws, size_t ws_size,
                              hipStream_t stream) {
  const int* skills    = (const int*)d_in[0];
  const int* responses = (const int*)d_in[1];
  const float* k_emb   = (const float*)d_in[2];
  const float* v_emb   = (const float*)d_in[3];
  const float* Mk      = (const float*)d_in[4];
  const float* Mv0     = (const float*)d_in[5];
  const float* fW      = (const float*)d_in[6];
  const float* fb      = (const float*)d_in[7];
  const float* eW      = (const float*)d_in[8];
  const float* eb      = (const float*)d_in[9];
  const float* aW      = (const float*)d_in[10];
  const float* ab      = (const float*)d_in[11];
  const float* pW      = (const float*)d_in[12];
  const float* pb      = (const float*)d_in[13];

  // f16-packed scratch: ea (3.3MB) | w16 (1.6MB) | p0..p3 (1.6MB each)
  unsigned* ea_ws        = (unsigned*)d_ws;
  unsigned short* w16_ws = (unsigned short*)(ea_ws + (size_t)NROW * 64);
  unsigned short* p0     = w16_ws + (size_t)NROW * 64;
  unsigned short* p1     = p0 + (size_t)NROW * 64;
  unsigned short* p2     = p1 + (size_t)NROW * 64;
  unsigned short* p3     = p2 + (size_t)NROW * 64;

  wea_mfma<<<dim3(400), 128, 0, stream>>>(
      skills, responses, k_emb, v_emb, Mk, eW, eb, aW, ab, ea_ws, w16_ws);
  scan_kernel<<<dim3(BB * 4), 256, 0, stream>>>(Mv0, ea_ws, w16_ws, p0, p1, p2, p3);
  fp_kernel<<<dim3(NOUT / 8), 256, 0, stream>>>(
      skills, k_emb, fW, fb, pW, pb, p0, p1, p2, p3, (float*)d_out);
}

// Round 5
// 119.874 us; speedup vs baseline: 2.8376x; 1.0173x over previous
//
#include <hip/hip_runtime.h>
#include <stdint.h>

#define NSK 1000
#define TT  200
#define BB  64
#define NROW (BB * TT)      // 12800
#define NOUT (BB * (TT-1))  // 12736
#define CH  20              // scan pipeline depth (steps); TT/CH = 10 chunks (even)
#define RW  2               // scan Mv rows per wave (8-way M split: 8 blocks/batch)
#define NSPLIT 8            // scan M-split factor
#define PSTR ((size_t)NROW * 64)   // partial-array stride (elements)

__device__ __forceinline__ unsigned ulane_bcast(unsigned v, int l) {
  return __builtin_amdgcn_readlane(v, l);
}
__device__ __forceinline__ float frcp(float x) { return __builtin_amdgcn_rcpf(x); }
__device__ __forceinline__ float sigm(float x) { return frcp(1.f + __expf(-x)); }
__device__ __forceinline__ float tanh_fast(float x) {
  return fmaf(-2.f, frcp(1.f + __expf(2.f * x)), 1.f);   // 1 - 2/(1+e^2x)
}

typedef _Float16 half2v __attribute__((ext_vector_type(2)));
typedef _Float16 v8h __attribute__((ext_vector_type(8)));   // MFMA A/B frag (4 VGPR)
typedef float    v4f __attribute__((ext_vector_type(4)));   // MFMA C/D frag
union H2U { unsigned u; half2v h; };
union V8U { uint4 u; v8h h; };
__device__ __forceinline__ unsigned pack2h(float a, float b) {
  H2U x; x.h = (half2v){(_Float16)a, (_Float16)b}; return x.u;
}
__device__ __forceinline__ unsigned short f16bits(float x) {
  H2U u; u.h = (half2v){(_Float16)x, (_Float16)0.f}; return (unsigned short)(u.u & 0xffffu);
}
__device__ __forceinline__ float f16lo(unsigned bits) {
  H2U u; u.u = bits; return (float)u.h.x;
}
__device__ __forceinline__ float f16hi(unsigned bits) {
  H2U u; u.u = bits; return (float)u.h.y;
}
__device__ __forceinline__ v8h pk8(float4 x0, float4 x1) {
  return (v8h){(_Float16)x0.x, (_Float16)x0.y, (_Float16)x0.z, (_Float16)x0.w,
               (_Float16)x1.x, (_Float16)x1.y, (_Float16)x1.z, (_Float16)x1.w};
}

// ============ Pass A (MFMA, R4-verified): 400 blocks x 128 thr, 16 rows/wave ============
// A: row=lane&15, k=(lane>>4)*8+e.  B: col=lane&15, same k.  D: col=lane&15, row=(lane>>4)*4+reg.
__global__ __launch_bounds__(128) void wea_mfma(
    const int* __restrict__ skills, const int* __restrict__ responses,
    const float* __restrict__ k_emb, const float* __restrict__ v_emb,
    const float* __restrict__ Mk, const float* __restrict__ eW,
    const float* __restrict__ eb, const float* __restrict__ aW,
    const float* __restrict__ ab,
    unsigned* __restrict__ ea_ws, unsigned short* __restrict__ w16_ws)
{
  const int tid  = threadIdx.x;
  const int wv   = tid >> 6, lane = tid & 63;
  const int tile = blockIdx.x * 2 + wv;              // 400*2 = 800 tiles
  const int r0   = tile * 16;
  const int lr   = lane & 15;                        // A-row / B-col / D-col
  const int lg   = lane >> 4;                        // k-group (8 f16 each)

  const int sk = skills[r0 + lr];
  int rr = responses[r0 + lr]; rr = (rr > -1) ? rr : 0;   // masked_r
  const int vrow = sk + NSK * rr;

  const float4* kq = (const float4*)(k_emb + (size_t)sk * 64);
  const float4* vq = (const float4*)(v_emb + (size_t)vrow * 64);
  v8h ak[2], av[2];
  #pragma unroll
  for (int t = 0; t < 2; ++t) {
    const int o = t * 8 + lg * 2;                    // float4 index within row
    ak[t] = pk8(kq[o], kq[o + 1]);
    av[t] = pk8(vq[o], vq[o + 1]);
  }

  float ebv[4], abv[4];
  #pragma unroll
  for (int c = 0; c < 4; ++c) { ebv[c] = eb[16 * c + lr]; abv[c] = ab[16 * c + lr]; }

  v4f acK[4], acE[4], acA[4];
  #pragma unroll
  for (int c = 0; c < 4; ++c) {
    acK[c] = (v4f){0.f, 0.f, 0.f, 0.f};
    acE[c] = (v4f){0.f, 0.f, 0.f, 0.f};
    acA[c] = (v4f){0.f, 0.f, 0.f, 0.f};
  }

  #pragma unroll
  for (int c = 0; c < 4; ++c) {
    const float4* mq = (const float4*)(Mk + (size_t)(16 * c + lr) * 64);
    const float4* eq = (const float4*)(eW + (size_t)(16 * c + lr) * 64);
    const float4* aq = (const float4*)(aW + (size_t)(16 * c + lr) * 64);
    #pragma unroll
    for (int t = 0; t < 2; ++t) {
      const int o = t * 8 + lg * 2;
      const v8h bm = pk8(mq[o], mq[o + 1]);
      const v8h be = pk8(eq[o], eq[o + 1]);
      const v8h ba = pk8(aq[o], aq[o + 1]);
      acK[c] = __builtin_amdgcn_mfma_f32_16x16x32_f16(ak[t], bm, acK[c], 0, 0, 0);
      acE[c] = __builtin_amdgcn_mfma_f32_16x16x32_f16(av[t], be, acE[c], 0, 0, 0);
      acA[c] = __builtin_amdgcn_mfma_f32_16x16x32_f16(av[t], ba, acA[c], 0, 0, 0);
    }
  }

  float rs[4];
  #pragma unroll
  for (int q = 0; q < 4; ++q) {
    float m = fmaxf(fmaxf(acK[0][q], acK[1][q]), fmaxf(acK[2][q], acK[3][q]));
    #pragma unroll
    for (int off = 8; off; off >>= 1) m = fmaxf(m, __shfl_xor(m, off));
    float s = 0.f;
    #pragma unroll
    for (int c = 0; c < 4; ++c) {
      acK[c][q] = __expf(acK[c][q] - m);
      s += acK[c][q];
    }
    #pragma unroll
    for (int off = 8; off; off >>= 1) s += __shfl_xor(s, off);
    rs[q] = frcp(s);
  }

  #pragma unroll
  for (int c = 0; c < 4; ++c) {
    const int j = 16 * c + lr;
    #pragma unroll
    for (int q = 0; q < 4; ++q) {
      const int row = r0 + lg * 4 + q;
      w16_ws[(size_t)row * 64 + j] = f16bits(acK[c][q] * rs[q]);
      const float ev = sigm(acE[c][q] + ebv[c]);
      const float avv = tanh_fast(acA[c][q] + abv[c]);
      ea_ws[(size_t)row * 64 + j] = pack2h(ev, avv);
    }
  }
}

// ---- scan helpers (f16-packed inputs, CH=20) ----
__device__ __forceinline__ void load_chunk(
    const unsigned* __restrict__ eap, const unsigned short* __restrict__ wp,
    int t0, int wl, int lane, unsigned* eab, unsigned* wvb)
{
  #pragma unroll
  for (int k = 0; k < CH; ++k) {
    eab[k] = eap[(t0 + k) * 64 + lane];
    wvb[k] = (unsigned)wp[(t0 + k) * 64 + wl];
  }
}

__device__ __forceinline__ void compute_chunk(
    float* Mv, const unsigned* eab, const unsigned* wvb,
    float* __restrict__ red, int wave, int lane)
{
  #pragma unroll
  for (int k = 0; k < CH; ++k) {
    const float ev = f16lo(eab[k]), av = f16hi(eab[k]);
    float rp = 0.f;
    #pragma unroll
    for (int i = 0; i < RW; ++i) {
      const float wm = f16lo(ulane_bcast(wvb[k], i));  // w[m0+i] sits in lane i (0..1)
      rp = fmaf(wm, Mv[i], rp);            // read uses PRE-update Mv
      float tp = fmaf(-ev, Mv[i], av);     // a - e*Mv
      Mv[i] = fmaf(wm, tp, Mv[i]);         // Mv += w*(a - e*Mv)
    }
    red[k * 256 + wave * 64 + lane] = rp;  // per-wave partial -> LDS
  }
}

// in-block reduce: wave w sums steps w*5..w*5+4 of the chunk -> f16 partial
__device__ __forceinline__ void reduce_store(
    const float* __restrict__ red, int ch, int base, int wave, int lane,
    unsigned short* __restrict__ ps)
{
  #pragma unroll
  for (int u = 0; u < 5; ++u) {
    const int k = wave * 5 + u;
    const float* rr = red + k * 256;
    const float v = (rr[lane] + rr[64 + lane]) + (rr[128 + lane] + rr[192 + lane]);
    ps[(size_t)(base + ch * CH + k) * 64 + lane] = f16bits(v);
  }
}

// ============ Pass B: 512 blocks x 256 thr, 8 blocks/batch (8 M-rows each) ============
__global__ __launch_bounds__(256) void scan_kernel(
    const float* __restrict__ Mv0,
    const unsigned* __restrict__ ea_ws, const unsigned short* __restrict__ w16_ws,
    unsigned short* __restrict__ pbase)
{
  __shared__ float red[2][CH * 256];                 // 40 KB -> 2 blocks/CU
  const int b    = blockIdx.x >> 3;
  const int s    = blockIdx.x & 7;
  const int wave = threadIdx.x >> 6;
  const int lane = threadIdx.x & 63;
  const int base = b * TT;
  const int m0   = s * 8 + wave * RW;
  const int wl   = m0 + (lane & (RW - 1));
  unsigned short* ps = pbase + (size_t)s * PSTR;

  float Mv[RW];
  #pragma unroll
  for (int i = 0; i < RW; ++i) Mv[i] = Mv0[(size_t)(m0 + i) * 64 + lane];

  const unsigned* eap = ea_ws + (size_t)base * 64;
  const unsigned short* wp = w16_ws + (size_t)base * 64;

  unsigned ea0[CH], wv0[CH], ea1[CH], wv1[CH];
  load_chunk(eap, wp, 0, wl, lane, ea0, wv0);
  for (int ch = 0; ch < TT / CH; ch += 2) {          // 10 chunks
    if ((ch + 1) * CH < TT)
      load_chunk(eap, wp, (ch + 1) * CH, wl, lane, ea1, wv1);
    compute_chunk(Mv, ea0, wv0, red[0], wave, lane);
    __syncthreads();
    reduce_store(red[0], ch, base, wave, lane, ps);
    if ((ch + 2) * CH < TT)
      load_chunk(eap, wp, (ch + 2) * CH, wl, lane, ea0, wv0);
    if ((ch + 1) * CH < TT) {
      compute_chunk(Mv, ea1, wv1, red[1], wave, lane);
      __syncthreads();
      reduce_store(red[1], ch + 1, base, wave, lane, ps);
    }
  }
}

// ============ Pass C (MFMA): 199 blocks x 256 thr, 16 outputs/wave ============
// [16x128] x [128x64] GEMM per wave: A = [reads | k_emb], B = fW (col=j, k-major),
// 16 MFMAs; epilogue tanh -> dot(pW) -> sigmoid.  199*4*16 = 12736 exact.
__global__ __launch_bounds__(256) void fp_mfma(
    const int* __restrict__ skills, const float* __restrict__ k_emb,
    const float* __restrict__ fW, const float* __restrict__ fb,
    const float* __restrict__ pW, const float* __restrict__ pb,
    const unsigned short* __restrict__ pbase,
    float* __restrict__ out)
{
  const int tid  = threadIdx.x;
  const int wv   = tid >> 6, lane = tid & 63;
  const int lr   = lane & 15;                        // A-row / B-col index
  const int lg   = lane >> 4;                        // k-group
  const int o0   = (blockIdx.x * 4 + wv) * 16;       // first output idx of this wave

  // this lane's A-row: output idx = o0 + lr
  const unsigned idx = o0 + lr;
  const unsigned bb  = idx / 199u;
  const unsigned t2  = idx - bb * 199u;
  const int srow     = (int)(idx + bb + 1u);         // source row b*200 + t + 1

  // A fragments: t=0,1 -> reads (sum of 8 f16 partials, packed-f16 adds);
  //              t=2,3 -> k_emb row.
  v8h ar[4];
  #pragma unroll
  for (int t = 0; t < 2; ++t) {
    const size_t eo = (size_t)srow * 64 + t * 32 + lg * 8;   // ushort offset
    V8U s0, s1, s2, s3;
    s0.u = *(const uint4*)&pbase[eo];
    s1.u = *(const uint4*)&pbase[eo + PSTR];
    s2.u = *(const uint4*)&pbase[eo + 2 * PSTR];
    s3.u = *(const uint4*)&pbase[eo + 3 * PSTR];
    v8h acc = (s0.h + s1.h) + (s2.h + s3.h);
    s0.u = *(const uint4*)&pbase[eo + 4 * PSTR];
    s1.u = *(const uint4*)&pbase[eo + 5 * PSTR];
    s2.u = *(const uint4*)&pbase[eo + 6 * PSTR];
    s3.u = *(const uint4*)&pbase[eo + 7 * PSTR];
    ar[t] = acc + ((s0.h + s1.h) + (s2.h + s3.h));
  }
  {
    const float4* kq = (const float4*)(k_emb + (size_t)skills[srow] * 64);
    #pragma unroll
    for (int t = 2; t < 4; ++t) {
      const int o = (t - 2) * 8 + lg * 2;
      ar[t] = pk8(kq[o], kq[o + 1]);
    }
  }

  float fbv[4], pwv[4];
  #pragma unroll
  for (int c = 0; c < 4; ++c) { fbv[c] = fb[16 * c + lr]; pwv[c] = pW[16 * c + lr]; }

  v4f acc[4];
  #pragma unroll
  for (int c = 0; c < 4; ++c) acc[c] = (v4f){0.f, 0.f, 0.f, 0.f};

  // B: fW[j][k], j = 16c+lr, k = t*32 + lg*8 + e  (fW row-major [64][128])
  const float4* fq = (const float4*)fW;
  #pragma unroll
  for (int c = 0; c < 4; ++c) {
    const int jb = (16 * c + lr) * 32;               // float4 row base
    #pragma unroll
    for (int t = 0; t < 4; ++t) {
      const int o = jb + t * 8 + lg * 2;
      const v8h bf = pk8(fq[o], fq[o + 1]);
      acc[c] = __builtin_amdgcn_mfma_f32_16x16x32_f16(ar[t], bf, acc[c], 0, 0, 0);
    }
  }

  // epilogue: f = tanh(acc + fb); p = sigm(f . pW + pb)
  const float pb0 = pb[0];
  #pragma unroll
  for (int q = 0; q < 4; ++q) {
    float s = 0.f;
    #pragma unroll
    for (int c = 0; c < 4; ++c)
      s += tanh_fast(acc[c][q] + fbv[c]) * pwv[c];
    #pragma unroll
    for (int off = 8; off; off >>= 1) s += __shfl_xor(s, off);
    if (lr == lg * 4 + q)                            // this lane owns row lg*4+q
      out[(size_t)bb * (TT - 1) + t2] = sigm(s + pb0);
  }
}

extern "C" void kernel_launch(void* const* d_in, const int* in_sizes, int n_in,
                              void* d_out, int out_size, void* d_ws, size_t ws_size,
                              hipStream_t stream) {
  const int* skills    = (const int*)d_in[0];
  const int* responses = (const int*)d_in[1];
  const float* k_emb   = (const float*)d_in[2];
  const float* v_emb   = (const float*)d_in[3];
  const float* Mk      = (const float*)d_in[4];
  const float* Mv0     = (const float*)d_in[5];
  const float* fW      = (const float*)d_in[6];
  const float* fb      = (const float*)d_in[7];
  const float* eW      = (const float*)d_in[8];
  const float* eb      = (const float*)d_in[9];
  const float* aW      = (const float*)d_in[10];
  const float* ab      = (const float*)d_in[11];
  const float* pW      = (const float*)d_in[12];
  const float* pb      = (const float*)d_in[13];
  (void)in_sizes; (void)n_in; (void)out_size; (void)ws_size;

  // f16-packed scratch: ea (3.3MB) | w16 (1.6MB) | 8 partial arrays (1.6MB each)
  unsigned* ea_ws        = (unsigned*)d_ws;
  unsigned short* w16_ws = (unsigned short*)(ea_ws + (size_t)NROW * 64);
  unsigned short* pbase  = w16_ws + PSTR;

  wea_mfma<<<dim3(400), 128, 0, stream>>>(
      skills, responses, k_emb, v_emb, Mk, eW, eb, aW, ab, ea_ws, w16_ws);
  scan_kernel<<<dim3(BB * NSPLIT), 256, 0, stream>>>(Mv0, ea_ws, w16_ws, pbase);
  fp_mfma<<<dim3(199), 256, 0, stream>>>(
      skills, k_emb, fW, fb, pW, pb, pbase, (float*)d_out);
}